// Round 6
// baseline (648.756 us; speedup 1.0000x reference)
//
#include <hip/hip_runtime.h>
#include <hip/hip_bf16.h>
#include <stdint.h>

// Problem constants (T, B, N, D) = (4, 16, 1024, 512); M = B*N
#define T_ 4
#define M_ 16384
#define D_ 512
#define R_ (T_ * M_)    // 65536 rows total
#define EPS_TRIG 1e-4f  // ~5 sigma of the bf16-split accumulation noise

typedef short bf16x8 __attribute__((ext_vector_type(8)));   // 8 bf16 (4 VGPRs)
typedef float f32x4  __attribute__((ext_vector_type(4)));
typedef unsigned short us8 __attribute__((ext_vector_type(8)));

// x = hi + lo + residual, |residual| <= 2^-17 |x|.
static __device__ __forceinline__ void split2bf16(float x, unsigned short& h, unsigned short& l) {
    unsigned int u = __float_as_uint(x);
    h = (unsigned short)(u >> 16);
    float r = x - __uint_as_float(u & 0xFFFF0000u);   // exact
    unsigned int v = __float_as_uint(r);
    l = (unsigned short)((v + 0x7FFFu + ((v >> 16) & 1u)) >> 16);
}

static __device__ __forceinline__ void split8(const float4& a, const float4& b, us8& hv, us8& lv) {
    unsigned short hh, ll;
    split2bf16(a.x, hh, ll); hv[0] = hh; lv[0] = ll;
    split2bf16(a.y, hh, ll); hv[1] = hh; lv[1] = ll;
    split2bf16(a.z, hh, ll); hv[2] = hh; lv[2] = ll;
    split2bf16(a.w, hh, ll); hv[3] = hh; lv[3] = ll;
    split2bf16(b.x, hh, ll); hv[4] = hh; lv[4] = ll;
    split2bf16(b.y, hh, ll); hv[5] = hh; lv[5] = ll;
    split2bf16(b.z, hh, ll); hv[6] = hh; lv[6] = ll;
    split2bf16(b.w, hh, ll); hv[7] = hh; lv[7] = ll;
}

// Async global->LDS, 16 B per lane. LDS dest = wave-uniform base + lane*16;
// the GLOBAL source address is per-lane.
static __device__ __forceinline__ void gload_lds16(const void* g, void* l) {
    __builtin_amdgcn_global_load_lds(
        (const __attribute__((address_space(1))) unsigned int*)g,
        (__attribute__((address_space(3))) unsigned int*)l,
        16, 0, 0);
}

// ---------------------------------------------------------------------------
// Kernel 0a: Wq/Wk/Wv split -> TILED layout (unchanged).
// Wtiled: [bd(8)][kbi(16)][wj(24)][dd(64)][16B], wj=(hl*4+g)*3+z.
// Fragment offset in 24576-B chunk: hl*12288 + g*3072 + z*1024 + dd*16.
// ---------------------------------------------------------------------------
__global__ __launch_bounds__(256) void split_w_tiled(
    const float* __restrict__ Wq, const float* __restrict__ Wk, const float* __restrict__ Wv,
    unsigned short* __restrict__ Wt)
{
    const int flat = blockIdx.x * 256 + threadIdx.x;  // 0..196607
    const int dd   = flat & 63;
    const int rest = flat >> 6;        // = bk*24 + wj
    const int wj   = rest % 24;
    const int bk   = rest / 24;        // bd*16 + kbi
    const int kbi  = bk & 15;
    const int bd   = bk >> 4;
    const int z    = wj % 3;
    const int hg   = wj / 3;
    const int hl   = hg >> 2;
    const int g    = hg & 3;

    const float* src = ((z == 0) ? Wq : (z == 1) ? Wk : Wv)
                       + (size_t)(bd * 64 + dd) * D_ + kbi * 32 + g * 8;
    float4 a = *reinterpret_cast<const float4*>(src);
    float4 b = *reinterpret_cast<const float4*>(src + 4);
    us8 hv, lv;
    split8(a, b, hv, lv);
    *reinterpret_cast<us8*>((char*)Wt + (size_t)flat * 16) = hl ? lv : hv;
}

// ---------------------------------------------------------------------------
// Kernel 0b: Wp split -> TILED layout (unchanged).
// WpT: per-(bd,kbi) chunk = 8192 B, layout [hl(2)][g(4)][dd(64)][16B].
// ---------------------------------------------------------------------------
__global__ __launch_bounds__(256) void split_wp_tiled(
    const float* __restrict__ Wp, unsigned short* __restrict__ WpT)
{
    const int flat = blockIdx.x * 256 + threadIdx.x;  // 0..32767
    const int dd   = flat & 63;
    const int g    = (flat >> 6) & 3;
    const int kbi  = (flat >> 8) & 15;
    const int bd   = flat >> 12;

    const float* src = Wp + (size_t)(bd * 64 + dd) * D_ + kbi * 32 + g * 8;
    float4 a = *reinterpret_cast<const float4*>(src);
    float4 b = *reinterpret_cast<const float4*>(src + 4);
    us8 hv, lv;
    split8(a, b, hv, lv);
    char* chunk = (char*)WpT + (size_t)(bd * 16 + kbi) * 8192;
    *reinterpret_cast<us8*>(chunk + g * 1024 + dd * 16)        = hv;
    *reinterpret_cast<us8*>(chunk + 4096 + g * 1024 + dd * 16) = lv;
}

// ---------------------------------------------------------------------------
// Kernel 1: projection + LIF + fixup + attn.  v6.
//
// Changes vs v5:
//  - X split FUSED into staging (split_x kernel deleted): f32 X loaded into
//    regs one phase ahead (GEMM-v3 discipline), split2bf16'd (trivial VALU),
//    ds_write_b128 into the inactive LDS buffer. LDS image byte-identical
//    to the old Xt layout -> MFMA phase & conflict-freedom unchanged.
//  - attn emitted as bf16 (values 0..4, exact) in the GEMM's TILED layout
//    (attnT) so kernel 2 can stage A via pure global_load_lds.
// All MFMA operand values bit-identical to rounds 0-5.
// ---------------------------------------------------------------------------
__global__ __launch_bounds__(256, 4) void proj_lif_attn_v6(
    const float* __restrict__ X,
    const float* __restrict__ Wq, const float* __restrict__ Wk, const float* __restrict__ Wv,
    const unsigned short* __restrict__ WtS,
    unsigned short* __restrict__ attnT)
{
    __shared__ unsigned short Xs[2][4096];   // 2 x 8 KB: [hl(2)][g(4)][row'(64)][16B]

    const int tid  = threadIdx.x;
    const int lane = tid & 63;
    const int wsub = tid >> 6;     // 0..3 -> 16-d subtile
    const int la   = lane & 15;
    const int lq   = lane >> 4;

    // bijective XCD co-location remap (8 XCDs, x-fastest dispatch)
    const int n   = blockIdx.y * 8 + blockIdx.x;   // 0..8191
    const int bd  = (n >> 3) & 7;
    const int bmp = (n & 7) * 128 + (n >> 6);      // 0..1023 (16-m group)

    f32x4 acc[3][T_];
    #pragma unroll
    for (int z = 0; z < 3; z++)
        #pragma unroll
        for (int t = 0; t < T_; t++)
            acc[z][t] = (f32x4){0.f, 0.f, 0.f, 0.f};

    // staging coordinates: thread j handles granule (g = j>>6, row' = j&63),
    // row' = t*16 + mm.  Reads 32 B f32 per K-step; writes hi/lo b128 to LDS.
    const int srow = tid & 63;
    const int sg   = tid >> 6;
    const int st   = srow >> 4;
    const int smm  = srow & 15;
    const float* xsrc = X + (size_t)(st * M_ + bmp * 16 + smm) * D_ + sg * 8;
    char* xw0 = (char*)&Xs[0][0] + sg * 1024 + srow * 16;   // hi dest, buf0 (lo at +4096)
    char* xw1 = (char*)&Xs[1][0] + sg * 1024 + srow * 16;

    const char* wb = (const char*)WtS + (size_t)(bd * 16) * 24576 + lq * 3072 + wsub * 256 + la * 16;

    bf16x8 whA[3], wlA[3], whB[3], wlB[3];
    float4 S0, S1, P0, P1;

    auto loadW = [&](bf16x8 (&wh)[3], bf16x8 (&wl)[3], int kbi) {
        const char* p = wb + (size_t)kbi * 24576;
        #pragma unroll
        for (int z = 0; z < 3; z++) {
            wh[z] = *reinterpret_cast<const bf16x8*>(p + z * 1024);
            wl[z] = *reinterpret_cast<const bf16x8*>(p + z * 1024 + 12288);
        }
    };
    auto loadX = [&](float4& a, float4& b, int kbi) {
        a = *reinterpret_cast<const float4*>(xsrc + kbi * 32);
        b = *reinterpret_cast<const float4*>(xsrc + kbi * 32 + 4);
    };
    auto storeX = [&](char* dst, const float4& a, const float4& b) {
        us8 hv, lv;
        split8(a, b, hv, lv);
        *reinterpret_cast<us8*>(dst)        = hv;
        *reinterpret_cast<us8*>(dst + 4096) = lv;
    };
    auto mfmaPhase = [&](const unsigned short* Xc, const bf16x8 (&wh)[3], const bf16x8 (&wl)[3]) {
        #pragma unroll
        for (int t = 0; t < T_; t++) {
            const int ab = lq * 1024 + (t * 16 + la) * 16;   // conflict-free
            bf16x8 ah = *reinterpret_cast<const bf16x8*>((const char*)Xc + ab);
            bf16x8 al = *reinterpret_cast<const bf16x8*>((const char*)Xc + 4096 + ab);
            #pragma unroll
            for (int z = 0; z < 3; z++) {
                acc[z][t] = __builtin_amdgcn_mfma_f32_16x16x32_bf16(ah, wh[z], acc[z][t], 0, 0, 0);
                acc[z][t] = __builtin_amdgcn_mfma_f32_16x16x32_bf16(ah, wl[z], acc[z][t], 0, 0, 0);
                acc[z][t] = __builtin_amdgcn_mfma_f32_16x16x32_bf16(al, wh[z], acc[z][t], 0, 0, 0);
            }
        }
    };

    // prologue: X(0) -> buf0; W(0) -> A set; prefetch X(1) -> S
    loadX(S0, S1, 0);
    storeX(xw0, S0, S1);
    loadW(whA, wlA, 0);
    loadX(S0, S1, 1);
    __syncthreads();

    for (int kp = 0; kp < 8; kp++) {
        // even kbi = 2kp: stage S(=X(2kp+1)) -> buf1; W(2kp+1)->B; prefetch X(2kp+2)->P
        storeX(xw1, S0, S1);
        loadW(whB, wlB, 2 * kp + 1);
        if (kp < 7) loadX(P0, P1, 2 * kp + 2);
        mfmaPhase(&Xs[0][0], whA, wlA);
        __syncthreads();
        // odd kbi = 2kp+1: stage P -> buf0; W(2kp+2)->A; prefetch X(2kp+3)->S
        if (kp < 7) {
            storeX(xw0, P0, P1);
            loadW(whA, wlA, 2 * kp + 2);
            loadX(S0, S1, 2 * kp + 3);
        }
        mfmaPhase(&Xs[1][0], whB, wlB);
        __syncthreads();
    }

    // Epilogue: LIF (fp32) + wave-cooperative exact-f64 fixup + attnT (bf16, tiled)
    const int d = bd * 64 + wsub * 16 + la;
    #pragma unroll
    for (int i = 0; i < 4; i++) {
        const int m = bmp * 16 + lq * 4 + i;
        int sp[3][T_];
        int zrisky = 0;
        #pragma unroll
        for (int z = 0; z < 3; z++) {
            float mem = 0.f;
            #pragma unroll
            for (int t = 0; t < T_; t++) {
                mem = 0.9f * mem + acc[z][t][i];
                if (fabsf(mem - 1.0f) < EPS_TRIG) zrisky |= (1 << z);
                const int sb = (mem >= 1.0f) ? 1 : 0;
                sp[z][t] = sb;
                mem -= (float)sb;
            }
        }
        unsigned long long ball = __ballot(zrisky != 0);
        while (ball) {
            const int src = (int)__builtin_ctzll(ball);
            ball &= ball - 1;
            const int bits = __shfl(zrisky, src);
            const int m_s  = bmp * 16 + (src >> 4) * 4 + i;
            const int d_s  = bd * 64 + wsub * 16 + (src & 15);
            #pragma unroll
            for (int z = 0; z < 3; z++) {
                if (!(bits & (1 << z))) continue;
                const float* Wrow = ((z == 0) ? Wq : (z == 1) ? Wk : Wv) + (size_t)d_s * D_;
                float4 w0 = *reinterpret_cast<const float4*>(Wrow + lane * 8);
                float4 w1 = *reinterpret_cast<const float4*>(Wrow + lane * 8 + 4);
                double pre[T_];
                #pragma unroll
                for (int t = 0; t < T_; t++) {
                    const float* xrow = X + (size_t)(t * M_ + m_s) * D_ + lane * 8;
                    float4 x0 = *reinterpret_cast<const float4*>(xrow);
                    float4 x1 = *reinterpret_cast<const float4*>(xrow + 4);
                    double p = (double)x0.x * (double)w0.x + (double)x0.y * (double)w0.y
                             + (double)x0.z * (double)w0.z + (double)x0.w * (double)w0.w
                             + (double)x1.x * (double)w1.x + (double)x1.y * (double)w1.y
                             + (double)x1.z * (double)w1.z + (double)x1.w * (double)w1.w;
                    #pragma unroll
                    for (int off = 32; off > 0; off >>= 1)
                        p += __shfl_xor(p, off, 64);
                    pre[t] = p;
                }
                double dm = 0.0;
                int spz[T_];
                #pragma unroll
                for (int t = 0; t < T_; t++) {
                    dm = 0.9 * dm + pre[t];
                    const int sb = (dm >= 1.0) ? 1 : 0;
                    spz[t] = sb;
                    dm -= (double)sb;
                }
                if (lane == src) {
                    #pragma unroll
                    for (int t = 0; t < T_; t++) sp[z][t] = spz[t];
                }
            }
        }
        // attnT layout: chunk (r>>7, kb=d>>5) of 8192 B; inside:
        // [g=(d>>3)&3][row=r&127][16B], byte (d&7)*2.  Values 0..4 exact bf16.
        const size_t dpart = (size_t)(d >> 5) * 8192 + ((d >> 3) & 3) * 2048 + (d & 7) * 2;
        int ctx = 0;
        #pragma unroll
        for (int t = 0; t < T_; t++) {
            ctx += sp[1][t] & sp[2][t];
            const int r = t * M_ + m;
            const int v = sp[0][t] ? ctx : 0;
            const unsigned short bv = (unsigned short)(__float_as_uint((float)v) >> 16);
            *(unsigned short*)((char*)attnT + (size_t)(r >> 7) * 131072
                               + (size_t)(r & 127) * 16 + dpart) = bv;
        }
    }
}

// ---------------------------------------------------------------------------
// Kernel 2: out = attnT @ Wp^T + bp via bf16 MFMA.  v4.
//  - A staged via pure global_load_lds from tiled bf16 attnT (zero staging
//    VALU, zero convert), double-buffered, ONE barrier per K-step.
//  - W fragments reg-double-buffered from WpT (v3's proven pattern).
//  - LDS 16 KB, low VGPR -> high occupancy for the short MFMA phases.
// ---------------------------------------------------------------------------
__global__ __launch_bounds__(256, 4) void attn_out_gemm_v4(
    const unsigned short* __restrict__ AT,  // tiled bf16 attn
    const unsigned short* __restrict__ WpT, // tiled split Wp
    const float*         __restrict__ bp,   // (D,)  f32
    float* __restrict__ out)                // (R, D) f32
{
    __shared__ unsigned short As[2][4096];  // 2 x 8 KB: [g(4)][row(128)][16B]

    const int tid  = threadIdx.x;
    const int lane = tid & 63;
    const int wsub = tid >> 6;
    const int la   = lane & 15;
    const int lq   = lane >> 4;

    const int n  = blockIdx.y * 8 + blockIdx.x;    // 0..4095
    const int bd = (n >> 3) & 7;
    const int bm = (n & 7) * 64 + (n >> 6);        // 0..511 (128-row group)

    f32x4 acc[8];
    #pragma unroll
    for (int s = 0; s < 8; s++) acc[s] = (f32x4){0.f, 0.f, 0.f, 0.f};

    // A chunk for (bm, kb) is byte-identical to the LDS buffer image.
    const char* asrc0 = (const char*)AT + (size_t)(bm * 16) * 8192 + wsub * 2048 + lane * 16;
    char* ad0 = (char*)&As[0][0] + wsub * 2048;
    char* ad1 = (char*)&As[1][0] + wsub * 2048;

    bf16x8 whA, wlA, whB, wlB;

    auto stageA = [&](int kb, char* xd) {
        const char* s = asrc0 + (size_t)kb * 8192;
        gload_lds16(s,        xd);
        gload_lds16(s + 1024, xd + 1024);
    };
    auto loadW = [&](bf16x8& wh, bf16x8& wl, int kb) {
        const char* p = (const char*)WpT + (size_t)(bd * 16 + kb) * 8192
                        + lq * 1024 + (wsub * 16 + la) * 16;
        wh = *reinterpret_cast<const bf16x8*>(p);
        wl = *reinterpret_cast<const bf16x8*>(p + 4096);
    };
    auto mfmaPhase = [&](const unsigned short* Ac, const bf16x8& wh, const bf16x8& wl) {
        #pragma unroll
        for (int s = 0; s < 8; s++) {
            bf16x8 a = *reinterpret_cast<const bf16x8*>(
                (const char*)Ac + lq * 2048 + (s * 16 + la) * 16);
            acc[s] = __builtin_amdgcn_mfma_f32_16x16x32_bf16(a, wh, acc[s], 0, 0, 0);
            acc[s] = __builtin_amdgcn_mfma_f32_16x16x32_bf16(a, wl, acc[s], 0, 0, 0);
        }
    };

    // prologue
    stageA(0, ad0);
    loadW(whA, wlA, 0);
    __syncthreads();

    for (int kp = 0; kp < 8; kp++) {
        stageA(2 * kp + 1, ad1);
        loadW(whB, wlB, 2 * kp + 1);
        mfmaPhase(&As[0][0], whA, wlA);
        __syncthreads();
        if (kp < 7) {
            stageA(2 * kp + 2, ad0);
            loadW(whA, wlA, 2 * kp + 2);
        }
        mfmaPhase(&As[1][0], whB, wlB);
        __syncthreads();
    }

    const int d = bd * 64 + wsub * 16 + la;
    const float bias = bp[d];
    #pragma unroll
    for (int s = 0; s < 8; s++)
        #pragma unroll
        for (int i = 0; i < 4; i++) {
            const int r = bm * 128 + s * 16 + lq * 4 + i;
            out[(size_t)r * D_ + d] = acc[s][i] + bias;
        }
}

extern "C" void kernel_launch(void* const* d_in, const int* in_sizes, int n_in,
                              void* d_out, int out_size, void* d_ws, size_t ws_size,
                              hipStream_t stream) {
    const float* x  = (const float*)d_in[0];  // x_seq (T,B,N,D) f32
    const float* wq = (const float*)d_in[1];
    const float* wk = (const float*)d_in[2];
    const float* wv = (const float*)d_in[3];
    const float* wp = (const float*)d_in[4];
    const float* bp = (const float*)d_in[5];

    // workspace: attnT 67.1M | Wt 3M | WpT 1M  = 71.3 MB (ws proven >= 176 MB)
    unsigned short* attnT = (unsigned short*)d_ws;
    unsigned short* Wt    = (unsigned short*)((char*)d_ws + 67108864);
    unsigned short* WpT   = (unsigned short*)((char*)d_ws + 67108864 + 3145728);

    dim3 blk(256);
    split_w_tiled <<<dim3(768), blk, 0, stream>>>(wq, wk, wv, Wt);
    split_wp_tiled<<<dim3(128), blk, 0, stream>>>(wp, WpT);

    dim3 g1(8, 1024);   // n = y*8+x; in-kernel XCD co-location remap
    proj_lif_attn_v6<<<g1, blk, 0, stream>>>(x, wq, wk, wv, Wt, attnT);

    dim3 g2(8, 512);
    attn_out_gemm_v4<<<g2, blk, 0, stream>>>(attnT, WpT, bp, (float*)d_out);
}